// Round 1
// baseline (1065.592 us; speedup 1.0000x reference)
//
#include <hip/hip_runtime.h>

typedef __bf16 bf16;
typedef bf16 bf16x8 __attribute__((ext_vector_type(8)));
typedef bf16 bf16x4 __attribute__((ext_vector_type(4)));
typedef float f32x4 __attribute__((ext_vector_type(4)));

#define N_NODES 65536
#define E_EDGES 262144
#define EDIM    300
#define HDIM    256
#define KCAT    576   // 320 (x zero-padded 300->320) + 256 (h_tilde)
#define NCAT    1024  // 768 (z_i|z_o|z_u) + 256 (x@W_f)

__device__ __forceinline__ float sigmoidf_(float x) {
    return 1.0f / (1.0f + __expf(-x));
}

// ---------------------------------------------------------------------------
// Pack weights: B^T (bf16) for both GEMMs + fused bias vector.
// BTcat[n][k], n in [0,1024), k in [0,576):
//   n < 768 : k<300 -> Wc[k][n]; 300<=k<320 -> 0; k>=320 -> Wc[k-20][n]
//   n >= 768: k<300 -> Wf[k][n-768]; else 0
// BTu[n][k] = Uf[k][n]
// biascat[n] = n<768 ? bc[n] : 0
// ---------------------------------------------------------------------------
__global__ __launch_bounds__(256) void pack_weights_kernel(
    const float* __restrict__ Wc, const float* __restrict__ Wf,
    const float* __restrict__ Uf, const float* __restrict__ bc,
    bf16* __restrict__ BTcat, bf16* __restrict__ BTu, float* __restrict__ biascat) {
    const int SZ1 = NCAT * KCAT;   // 589824
    const int SZ2 = HDIM * HDIM;   // 65536
    int idx = blockIdx.x * 256 + threadIdx.x;
    if (idx < SZ1) {
        int n = idx / KCAT, k = idx % KCAT;
        float v = 0.f;
        if (n < 768) {
            if (k < EDIM) v = Wc[k * 768 + n];
            else if (k >= 320) v = Wc[(k - 20) * 768 + n];
        } else {
            if (k < EDIM) v = Wf[k * HDIM + (n - 768)];
        }
        BTcat[idx] = (bf16)v;
    } else if (idx < SZ1 + SZ2) {
        int i = idx - SZ1;
        int n = i / HDIM, k = i % HDIM;
        BTu[i] = (bf16)Uf[k * HDIM + n];
    } else if (idx < SZ1 + SZ2 + NCAT) {
        int n = idx - SZ1 - SZ2;
        biascat[n] = (n < 768) ? bc[n] : 0.f;
    }
}

// x (f32 [N,300]) -> Acat[:, 0:320] bf16 (zero pad 300..319)
__global__ __launch_bounds__(256) void convert_x_kernel(
    const float* __restrict__ x, bf16* __restrict__ Acat) {
    int i = blockIdx.x * 256 + threadIdx.x;   // over N*320
    int row = i / 320;
    int c = i - row * 320;
    float v = (c < EDIM) ? x[row * EDIM + c] : 0.f;
    Acat[(size_t)row * KCAT + c] = (bf16)v;
}

// prev_h f32 -> bf16 copy (vectorized 4-wide)
__global__ __launch_bounds__(256) void convert_ph_kernel(
    const float* __restrict__ ph, bf16* __restrict__ phb) {
    size_t i = ((size_t)blockIdx.x * 256 + threadIdx.x) * 4;
    float4 v = *(const float4*)(ph + i);
    bf16x4 o;
    o[0] = (bf16)v.x; o[1] = (bf16)v.y; o[2] = (bf16)v.z; o[3] = (bf16)v.w;
    *(bf16x4*)(phb + i) = o;
}

// start[j] = lower_bound(seg, j); edges of node j = [start[j], start[j+1])
__global__ __launch_bounds__(256) void seg_start_kernel(
    const int* __restrict__ seg, int* __restrict__ start) {
    int j = blockIdx.x * 256 + threadIdx.x;
    if (j > N_NODES) return;
    int lo = 0, hi = E_EDGES;
    while (lo < hi) {
        int mid = (lo + hi) >> 1;
        if (seg[mid] < j) lo = mid + 1; else hi = mid;
    }
    start[j] = lo;
}

// h_tilde[j] = sum over child edges of prev_h; write bf16 into Acat[:,320:576]
__global__ __launch_bounds__(256) void htilde_kernel(
    const bf16* __restrict__ phb, const int* __restrict__ start,
    bf16* __restrict__ Acat) {
    int j = blockIdx.x;
    int c = threadIdx.x;
    int s = start[j], e = start[j + 1];
    float acc = 0.f;
    for (int k = s; k < e; ++k) acc += (float)phb[(size_t)k * HDIM + c];
    Acat[(size_t)j * KCAT + 320 + c] = (bf16)acc;
}

// ---------------------------------------------------------------------------
// GEMM: C[M,Nc] = A[M,K](bf16,row-major) * BT[Nc,K](bf16,row-major)^T + bias
// 128x128 tile / block (4 waves, each 64x64 via 4x4 of 16x16x32 MFMA).
// M % 128 == 0, Nc % 128 == 0, K % 32 == 0 (guaranteed by padding).
// ---------------------------------------------------------------------------
template <typename OutT>
__global__ __launch_bounds__(256) void gemm_tn(
    const bf16* __restrict__ A, const bf16* __restrict__ BT,
    OutT* __restrict__ C, const float* __restrict__ bias, int K, int ldc) {
    __shared__ bf16 As[128][40];  // +8 pad: 2-way bank aliasing only (free)
    __shared__ bf16 Bs[128][40];

    const int tid = threadIdx.x;
    const int m0 = blockIdx.x * 128;
    const int n0 = blockIdx.y * 128;
    const int lane = tid & 63;
    const int w = tid >> 6;
    const int wm = (w >> 1) * 64;
    const int wn = (w & 1) * 64;
    const int l15 = lane & 15;
    const int kf = (lane >> 4) * 8;

    const int sr = tid >> 2;        // 0..63 (staging row)
    const int sk = (tid & 3) * 8;   // 0,8,16,24 (staging k offset)

    f32x4 acc[4][4] = {};

    for (int k0 = 0; k0 < K; k0 += 32) {
        __syncthreads();
        *(bf16x8*)&As[sr][sk]      = *(const bf16x8*)(A + (size_t)(m0 + sr) * K + k0 + sk);
        *(bf16x8*)&As[sr + 64][sk] = *(const bf16x8*)(A + (size_t)(m0 + sr + 64) * K + k0 + sk);
        *(bf16x8*)&Bs[sr][sk]      = *(const bf16x8*)(BT + (size_t)(n0 + sr) * K + k0 + sk);
        *(bf16x8*)&Bs[sr + 64][sk] = *(const bf16x8*)(BT + (size_t)(n0 + sr + 64) * K + k0 + sk);
        __syncthreads();

        bf16x8 af[4], bg[4];
#pragma unroll
        for (int i = 0; i < 4; ++i) af[i] = *(const bf16x8*)&As[wm + i * 16 + l15][kf];
#pragma unroll
        for (int j = 0; j < 4; ++j) bg[j] = *(const bf16x8*)&Bs[wn + j * 16 + l15][kf];
#pragma unroll
        for (int i = 0; i < 4; ++i)
#pragma unroll
            for (int j = 0; j < 4; ++j)
                acc[i][j] = __builtin_amdgcn_mfma_f32_16x16x32_bf16(af[i], bg[j], acc[i][j], 0, 0, 0);
    }

    const int r0 = (lane >> 4) * 4;
#pragma unroll
    for (int i = 0; i < 4; ++i) {
#pragma unroll
        for (int j = 0; j < 4; ++j) {
            const int col = n0 + wn + j * 16 + l15;
            const float bv = bias ? bias[col] : 0.f;
            const int row = m0 + wm + i * 16 + r0;
#pragma unroll
            for (int r = 0; r < 4; ++r) {
                C[(size_t)(row + r) * ldc + col] = (OutT)(acc[i][j][r] + bv);
            }
        }
    }
}

// ---------------------------------------------------------------------------
// Fused epilogue, one block per node:
//   f_jk = sigmoid(xWf[j] + hU[e] + b_f); fc = sum f*prev_c over child edges
//   c = sig(z_i)*tanh(z_u) + fc;  h = sig(z_o)*tanh(c)
// ---------------------------------------------------------------------------
__global__ __launch_bounds__(256) void final_kernel(
    const float* __restrict__ C1, const bf16* __restrict__ hU,
    const float* __restrict__ prev_c, const float* __restrict__ b_f,
    const int* __restrict__ start, float* __restrict__ out) {
    int j = blockIdx.x;
    int t = threadIdx.x;
    const float* row = C1 + (size_t)j * NCAT;
    float zi  = row[t];
    float zo  = row[HDIM + t];
    float zu  = row[2 * HDIM + t];
    float xwf = row[3 * HDIM + t];
    float bfv = b_f[t];

    int s = start[j], e = start[j + 1];
    float acc = 0.f;
    for (int k = s; k < e; ++k) {
        float u = (float)hU[(size_t)k * HDIM + t];
        float f = sigmoidf_(xwf + u + bfv);
        acc += f * prev_c[(size_t)k * HDIM + t];
    }
    float c = sigmoidf_(zi) * tanhf(zu) + acc;
    float h = sigmoidf_(zo) * tanhf(c);
    out[(size_t)j * HDIM + t] = c;
    out[(size_t)N_NODES * HDIM + (size_t)j * HDIM + t] = h;
}

extern "C" void kernel_launch(void* const* d_in, const int* in_sizes, int n_in,
                              void* d_out, int out_size, void* d_ws, size_t ws_size,
                              hipStream_t stream) {
    const float* x   = (const float*)d_in[0];
    const float* pc  = (const float*)d_in[1];
    const float* ph  = (const float*)d_in[2];
    const float* Wc  = (const float*)d_in[3];
    const float* bc  = (const float*)d_in[4];
    const float* Wf  = (const float*)d_in[5];
    const float* Uf  = (const float*)d_in[6];
    const float* bf_ = (const float*)d_in[7];
    const int*   seg = (const int*)d_in[8];
    float* out = (float*)d_out;

    char* ws = (char*)d_ws;
    size_t off = 0;
    auto alloc = [&](size_t bytes) -> void* {
        void* p = ws + off;
        off += (bytes + 255) & ~(size_t)255;
        return p;
    };
    bf16*  Acat    = (bf16*)alloc((size_t)N_NODES * KCAT * 2);   // 75.5 MB
    bf16*  BTcat   = (bf16*)alloc((size_t)NCAT * KCAT * 2);      // 1.2 MB
    bf16*  BTu     = (bf16*)alloc((size_t)HDIM * HDIM * 2);      // 128 KB
    float* biascat = (float*)alloc((size_t)NCAT * 4);            // 4 KB
    bf16*  phb     = (bf16*)alloc((size_t)E_EDGES * HDIM * 2);   // 134 MB
    float* C1      = (float*)alloc((size_t)N_NODES * NCAT * 4);  // 268 MB
    bf16*  hU      = (bf16*)alloc((size_t)E_EDGES * HDIM * 2);   // 134 MB
    int*   start   = (int*)alloc((size_t)(N_NODES + 1) * 4);     // 256 KB

    pack_weights_kernel<<<2564, 256, 0, stream>>>(Wc, Wf, Uf, bc, BTcat, BTu, biascat);
    convert_x_kernel<<<(N_NODES * 320) / 256, 256, 0, stream>>>(x, Acat);
    convert_ph_kernel<<<(E_EDGES * HDIM / 4) / 256, 256, 0, stream>>>(ph, phb);
    seg_start_kernel<<<257, 256, 0, stream>>>(seg, start);
    htilde_kernel<<<N_NODES, 256, 0, stream>>>(phb, start, Acat);
    gemm_tn<float><<<dim3(N_NODES / 128, NCAT / 128), 256, 0, stream>>>(
        Acat, BTcat, C1, biascat, KCAT, NCAT);
    gemm_tn<bf16><<<dim3(E_EDGES / 128, HDIM / 128), 256, 0, stream>>>(
        phb, BTu, hU, nullptr, HDIM, HDIM);
    final_kernel<<<N_NODES, 256, 0, stream>>>(C1, hU, pc, bf_, start, out);
}